// Round 14
// baseline (322.963 us; speedup 1.0000x reference)
//
#include <hip/hip_runtime.h>
#include <hip/hip_bf16.h>
#include <math.h>

static constexpr int B  = 16384;
static constexpr int F  = 256;
static constexpr int NQ = 2048;
static constexpr int TS = 16;
static constexpr int KTOP = 8;
static constexpr int SPD = 272;   // 256 + 16
static constexpr int SPH = 68;
static constexpr int CD  = 278;   // 256+1+3+16+2
static constexpr int CH  = 69;

typedef __attribute__((ext_vector_type(8))) short bf16x8;
typedef __attribute__((ext_vector_type(4))) float f32x4;
typedef _Float16 f16x2 __attribute__((ext_vector_type(2)));
typedef unsigned u32x4 __attribute__((ext_vector_type(4)));

__device__ inline short f2bf(float f) {
    unsigned u = __builtin_bit_cast(unsigned, f);
    unsigned r = (u + 0x7FFF + ((u >> 16) & 1)) >> 16;   // RNE
    return (short)r;
}

// packed f32x2 -> bf16x2 (RNE), single v_cvt_pk_bf16_f32
__device__ inline unsigned pkbf(float a, float b) {
    __hip_bfloat162 h = __float22bfloat162_rn(make_float2(a, b));
    unsigned u;
    __builtin_memcpy(&u, &h, 4);
    return u;
}

__device__ inline float fast_tanh(float o) {
    o = fminf(fmaxf(o, -15.0f), 15.0f);
    float e = __expf(2.0f * o);
    return (e - 1.0f) / (e + 1.0f);
}

// cvt_pkrtz returns __fp16x2; fdot2 wants _Float16x2 — bit-identical, shim it.
__device__ inline f16x2 cvt2h(float a, float b) {
    return __builtin_bit_cast(f16x2, __builtin_amdgcn_cvt_pkrtz(a, b));
}

__device__ inline unsigned pack2h(float a, float b) {
    return __builtin_bit_cast(unsigned, __builtin_amdgcn_cvt_pkrtz(a, b));
}

// ---------------------------------------------------------------------------
// k_prepall: bf16 W^T buffers (padded) + f16-pair stem weights (blocks 0..928)
// + LDS-tiled COALESCED qs transpose (blocks 929..1056, 64x64 tiles).
// ---------------------------------------------------------------------------
__device__ inline void prep_one(const float* W, short* T, int local,
                                int K, int N, int KP) {
    const int n = local / KP, k = local - n * KP;
    T[local] = (k < K && n < N) ? f2bf(W[k * N + n]) : (short)0;
}

__global__ __launch_bounds__(256) void k_prepall(
    const float* __restrict__ gate_w1, const float* __restrict__ gate_w2,
    const float* __restrict__ bb_w,    const float* __restrict__ safe_w1,
    const float* __restrict__ spec_w1, const float* __restrict__ conf_w1,
    const float* __restrict__ qs,
    const float* __restrict__ stem_w2, const float* __restrict__ stem_w3,
    short* __restrict__ w1t, short* __restrict__ w2t, short* __restrict__ bbt,
    short* __restrict__ sw1t, short* __restrict__ spw1t, short* __restrict__ cfw1t,
    float* __restrict__ qs_t,
    unsigned* __restrict__ w2ph, unsigned* __restrict__ w3ph)
{
    __shared__ float tile[64][65];
    if (blockIdx.x < 929) {
        const int idx = blockIdx.x * 256 + threadIdx.x;
        if (idx < 32768)       prep_one(gate_w1, w1t,  idx,           256, 128, 256);
        else if (idx < 65536)  prep_one(gate_w2, w2t,  idx - 32768,   128, 256, 128);
        else if (idx < 131072) prep_one(bb_w,    bbt,  idx - 65536,   256, 256, 256);
        else if (idx < 163840) prep_one(safe_w1, sw1t, idx - 131072,  256, 128, 256);
        else if (idx < 200704) prep_one(spec_w1, spw1t, idx - 163840, 272, 68, 288);
        else if (idx < 237568) prep_one(conf_w1, cfw1t, idx - 200704, 278, 69, 288);
        else if (idx < 237696) {
            // stem_w2 packed as f16 pairs along K
            const int l = idx - 237568;            // 0..127
            const int t = l >> 4, j = l & 15;
            w2ph[l] = pack2h(stem_w2[(2 * t) * 16 + j], stem_w2[(2 * t + 1) * 16 + j]);
        }
        else if (idx < 237704) {
            const int u = idx - 237696;            // 0..7
            w3ph[u] = pack2h(stem_w3[2 * u], stem_w3[2 * u + 1]);
        }
    } else {
        // 64x64 tile transpose: qs [2048][256] -> qs_t [256][2048]
        const int t = blockIdx.x - 929;            // 0..127
        const int tq = t & 31, tf = t >> 5;        // 32 q-tiles x 4 f-tiles
        const int q0 = tq * 64, f0 = tf * 64;
        const int c = threadIdx.x & 63, r4 = threadIdx.x >> 6;
#pragma unroll
        for (int rr = 0; rr < 16; ++rr) {
            const int row = rr * 4 + r4;
            tile[row][c] = qs[(q0 + row) * 256 + f0 + c];   // coalesced in f
        }
        __syncthreads();
#pragma unroll
        for (int rr = 0; rr < 16; ++rr) {
            const int fr = rr * 4 + r4;
            qs_t[(long)(f0 + fr) * 2048 + q0 + c] = tile[c][fr];  // coalesced in q
        }
    }
}

// ---------------------------------------------------------------------------
// k_calib7: thread = feature, 32 rows/block (grid 512) — measured-best
// structure: pipelined table fill, 6-level LDS binary search, 8-wide
// batching (`#pragma unroll 1` on the group loop), dot2-f16 stem MLP,
// x_num cross-group prefetch.
// ---------------------------------------------------------------------------
__global__ __launch_bounds__(256) void k_calib7(
    const float* __restrict__ x_num, const float* __restrict__ center,
    const float* __restrict__ scale, const float* __restrict__ qs,
    const float* __restrict__ qs_t,
    const float* __restrict__ sw1, const float* __restrict__ sb1,
    const unsigned* __restrict__ w2ph, const float* __restrict__ sb2,
    const unsigned* __restrict__ w3ph, const float* __restrict__ sb3,
    float* __restrict__ x_cal)
{
    __shared__ float cq[63 * 256];          // 63 KB
    const int tid = threadIdx.x;
    const int f = tid;
    // pipelined fill: 7 rounds of 9 independent loads
#pragma unroll 1
    for (int j0 = 0; j0 < 63; j0 += 9) {
        float t[9];
#pragma unroll
        for (int u = 0; u < 9; ++u) t[u] = qs[(32 * (j0 + u + 1)) * 256 + tid];
#pragma unroll
        for (int u = 0; u < 9; ++u) cq[(j0 + u) * 256 + tid] = t[u];
    }
    __syncthreads();

    const float c = center[f];
    const float inv_sc = 1.0f / scale[f];
    const float* colp = qs_t + (long)f * NQ;
    const long row_base = (long)blockIdx.x * 32;

    // prefetch group 0
    float xb[8];
#pragma unroll
    for (int i = 0; i < 8; ++i) xb[i] = x_num[(row_base + i) * F + f];

#pragma unroll 1
    for (int grp = 0; grp < 4; ++grp) {
        const long r0 = row_base + grp * 8;
        float x[8], xr[8];
#pragma unroll
        for (int i = 0; i < 8; ++i) x[i] = xb[i];
        // prefetch next group's x while this group computes
        if (grp < 3) {
#pragma unroll
            for (int i = 0; i < 8; ++i) xb[i] = x_num[(r0 + 8 + i) * F + f];
        }
#pragma unroll
        for (int i = 0; i < 8; ++i) xr[i] = (x[i] - c) * inv_sc;

        // coarse: 6-level binary search over 63 LDS boundaries
        int lo[8], hi[8];
#pragma unroll
        for (int i = 0; i < 8; ++i) { lo[i] = 0; hi[i] = 63; }
#pragma unroll
        for (int it = 0; it < 6; ++it) {
            float qv[8]; int mid[8];
#pragma unroll
            for (int i = 0; i < 8; ++i) {
                mid[i] = (lo[i] + hi[i]) >> 1;
                qv[i] = cq[mid[i] * 256 + f];
            }
#pragma unroll
            for (int i = 0; i < 8; ++i) {
                if (qv[i] < x[i]) lo[i] = mid[i] + 1; else hi[i] = mid[i];
            }
        }
        // probe mid of 32-window -> 16-half
        int base[8];
        {
            float pm[8];
#pragma unroll
            for (int i = 0; i < 8; ++i) pm[i] = colp[lo[i] * 32 + 16];
#pragma unroll
            for (int i = 0; i < 8; ++i)
                base[i] = lo[i] * 32 + ((pm[i] < x[i]) ? 16 : 0);
        }
        // one aligned 64B line: 4x float4, count < x
        float xq[8];
#pragma unroll
        for (int i = 0; i < 8; ++i) {
            const float4* wp = reinterpret_cast<const float4*>(&colp[base[i]]);
            const float4 a = wp[0], b = wp[1], d = wp[2], e = wp[3];
            int cN = 0;
            cN += (a.x < x[i]); cN += (a.y < x[i]); cN += (a.z < x[i]); cN += (a.w < x[i]);
            cN += (b.x < x[i]); cN += (b.y < x[i]); cN += (b.z < x[i]); cN += (b.w < x[i]);
            cN += (d.x < x[i]); cN += (d.y < x[i]); cN += (d.z < x[i]); cN += (d.w < x[i]);
            cN += (e.x < x[i]); cN += (e.y < x[i]); cN += (e.z < x[i]); cN += (e.w < x[i]);
            const int rank = base[i] + cN;
            xq[i] = fminf((float)rank * (1.0f / (float)(NQ - 1)), 1.0f);
        }

        // stem MLP: two sub-groups of 4 rows (register pressure);
        // h2 and output layer via v_dot2_f32_f16 (f32 accumulate)
#pragma unroll
        for (int hgrp = 0; hgrp < 2; ++hgrp) {
            const int o4 = hgrp * 4;
            float h2[4][16];
#pragma unroll
            for (int j = 0; j < 16; ++j) {
                const float bb = sb2[j];
#pragma unroll
                for (int i = 0; i < 4; ++i) h2[i][j] = bb;
            }
#pragma unroll 4
            for (int t = 0; t < 8; ++t) {
                const float w0a = sw1[2 * t],     w1a = sw1[16 + 2 * t],     w2a = sw1[32 + 2 * t];
                const float w0b = sw1[2 * t + 1], w1b = sw1[16 + 2 * t + 1], w2b = sw1[32 + 2 * t + 1];
                const float ba = sb1[2 * t], bbv = sb1[2 * t + 1];
                f16x2 hp[4];
#pragma unroll
                for (int i = 0; i < 4; ++i) {
                    const float ha = fmaxf(ba  + x[o4 + i] * w0a + xr[o4 + i] * w1a + xq[o4 + i] * w2a, 0.0f);
                    const float hb = fmaxf(bbv + x[o4 + i] * w0b + xr[o4 + i] * w1b + xq[o4 + i] * w2b, 0.0f);
                    hp[i] = cvt2h(ha, hb);
                }
                unsigned ww[16];
                const uint4* wr = reinterpret_cast<const uint4*>(&w2ph[t * 16]);
                *reinterpret_cast<uint4*>(&ww[0])  = wr[0];
                *reinterpret_cast<uint4*>(&ww[4])  = wr[1];
                *reinterpret_cast<uint4*>(&ww[8])  = wr[2];
                *reinterpret_cast<uint4*>(&ww[12]) = wr[3];
#pragma unroll
                for (int j = 0; j < 16; ++j) {
                    const f16x2 wj = __builtin_bit_cast(f16x2, ww[j]);
#pragma unroll
                    for (int i = 0; i < 4; ++i)
                        h2[i][j] = __builtin_amdgcn_fdot2(hp[i], wj, h2[i][j], false);
                }
            }
            const float b3 = sb3[0];
            float o[4] = {b3, b3, b3, b3};
#pragma unroll
            for (int u = 0; u < 8; ++u) {
                const f16x2 wu = __builtin_bit_cast(f16x2, w3ph[u]);
#pragma unroll
                for (int i = 0; i < 4; ++i) {
                    const f16x2 hh = cvt2h(
                        fmaxf(h2[i][2 * u], 0.0f), fmaxf(h2[i][2 * u + 1], 0.0f));
                    o[i] = __builtin_amdgcn_fdot2(hh, wu, o[i], false);
                }
            }
#pragma unroll
            for (int i = 0; i < 4; ++i)
                x_cal[(r0 + o4 + i) * F + f] = x[o4 + i] + 0.1f * fast_tanh(o[i]);
        }
    }
}

// ---------------------------------------------------------------------------
// k_fused2: gate1 -> gate2 (writes g) -> backbone (writes h_b) -> topk.
// 32 rows/block, grid 512. topk phase (verbatim from R10's bit-exact k_cf
// phase D) reads g from global: each block reads only the rows it wrote in
// stage2 (same CU -> same XCD L2 slice -> hits). LDS stays 25.6KB, so
// occupancy for the MFMA stages is unchanged (unlike the k_cf calib-fusion).
// ---------------------------------------------------------------------------
static constexpr int ST1 = 136;   // bf16 stride for h1 (32x128)
static constexpr int ST2 = 264;   // bf16 stride for x_gated (32x256)

__global__ __launch_bounds__(256) void k_fused2(
    const float* __restrict__ x_cal,
    const short* __restrict__ w1t, const float* __restrict__ gate_b1,
    const short* __restrict__ w2t, const float* __restrict__ gate_b2,
    const short* __restrict__ bbt, const float* __restrict__ bb_b,
    const float* __restrict__ tw1, const float* __restrict__ tb1,
    const float* __restrict__ tw2, const float* __restrict__ tb2,
    float* __restrict__ g, float* __restrict__ h_b,
    float* __restrict__ z_top, float* __restrict__ stats)
{
    __shared__ short s_c1[32 * ST1];
    __shared__ short s_xg[32 * ST2];

    const int tid = threadIdx.x;
    const int wave = tid >> 6, lane = tid & 63;
    const int sub = lane & 15, quad = lane >> 4;
    const int wm = wave & 1, wn = wave >> 1;
    const long row0 = (long)blockIdx.x * 32;
    const long mrow = row0 + wm * 16 + sub;

    // ---- stage1: h1 = relu(x_cal @ W1 + b1), 32x128 ----
    {
        f32x4 acc[4];
#pragma unroll
        for (int t = 0; t < 4; ++t) acc[t] = (f32x4){0, 0, 0, 0};
#pragma unroll
        for (int k0 = 0; k0 < 256; k0 += 32) {
            const float* ap = x_cal + mrow * 256 + k0 + quad * 8;
            float av[8];
            *reinterpret_cast<float4*>(&av[0]) = *reinterpret_cast<const float4*>(ap);
            *reinterpret_cast<float4*>(&av[4]) = *reinterpret_cast<const float4*>(ap + 4);
            u32x4 afu;
            afu[0] = pkbf(av[0], av[1]);
            afu[1] = pkbf(av[2], av[3]);
            afu[2] = pkbf(av[4], av[5]);
            afu[3] = pkbf(av[6], av[7]);
            const bf16x8 af = __builtin_bit_cast(bf16x8, afu);
#pragma unroll
            for (int t = 0; t < 4; ++t) {
                const int col = wn * 64 + t * 16 + sub;
                const bf16x8 bf = *reinterpret_cast<const bf16x8*>(
                    &w1t[(long)col * 256 + k0 + quad * 8]);
                acc[t] = __builtin_amdgcn_mfma_f32_16x16x32_bf16(af, bf, acc[t], 0, 0, 0);
            }
        }
#pragma unroll
        for (int t = 0; t < 4; ++t) {
            const int col = wn * 64 + t * 16 + sub;
            const float bb = gate_b1[col];
#pragma unroll
            for (int r = 0; r < 4; ++r) {
                const int rowl = wm * 16 + quad * 4 + r;
                s_c1[rowl * ST1 + col] = f2bf(fmaxf(acc[t][r] + bb, 0.0f));
            }
        }
    }
    __syncthreads();

    // ---- stage2: g = sigmoid(h1 @ W2 + b2), 32x256; build x_gated bf16 ----
    {
        f32x4 acc[8];
#pragma unroll
        for (int t = 0; t < 8; ++t) acc[t] = (f32x4){0, 0, 0, 0};
#pragma unroll
        for (int k0 = 0; k0 < 128; k0 += 32) {
            const bf16x8 af = *reinterpret_cast<const bf16x8*>(
                &s_c1[(wm * 16 + sub) * ST1 + k0 + quad * 8]);
#pragma unroll
            for (int t = 0; t < 8; ++t) {
                const int col = wn * 128 + t * 16 + sub;
                const bf16x8 bf = *reinterpret_cast<const bf16x8*>(
                    &w2t[(long)col * 128 + k0 + quad * 8]);
                acc[t] = __builtin_amdgcn_mfma_f32_16x16x32_bf16(af, bf, acc[t], 0, 0, 0);
            }
        }
#pragma unroll
        for (int t = 0; t < 8; ++t) {
            const int col = wn * 128 + t * 16 + sub;
            const float bb = gate_b2[col];
#pragma unroll
            for (int r = 0; r < 4; ++r) {
                const int rowl = wm * 16 + quad * 4 + r;
                const float gv = 1.0f / (1.0f + __expf(-(acc[t][r] + bb)));
                g[(row0 + rowl) * 256 + col] = gv;
                const float xg = x_cal[(row0 + rowl) * 256 + col] * gv;
                s_xg[rowl * ST2 + col] = f2bf(xg);
            }
        }
    }
    __syncthreads();

    // ---- stage3: h_b = relu(x_gated @ BB + bb_b), 32x256 ----
    {
        f32x4 acc[8];
#pragma unroll
        for (int t = 0; t < 8; ++t) acc[t] = (f32x4){0, 0, 0, 0};
#pragma unroll
        for (int k0 = 0; k0 < 256; k0 += 32) {
            const bf16x8 af = *reinterpret_cast<const bf16x8*>(
                &s_xg[(wm * 16 + sub) * ST2 + k0 + quad * 8]);
#pragma unroll
            for (int t = 0; t < 8; ++t) {
                const int col = wn * 128 + t * 16 + sub;
                const bf16x8 bf = *reinterpret_cast<const bf16x8*>(
                    &bbt[(long)col * 256 + k0 + quad * 8]);
                acc[t] = __builtin_amdgcn_mfma_f32_16x16x32_bf16(af, bf, acc[t], 0, 0, 0);
            }
        }
#pragma unroll
        for (int t = 0; t < 8; ++t) {
            const int col = wn * 128 + t * 16 + sub;
            const float bb = bb_b[col];
#pragma unroll
            for (int r = 0; r < 4; ++r) {
                const int rowl = wm * 16 + quad * 4 + r;
                h_b[(row0 + rowl) * 256 + col] = fmaxf(acc[t][r] + bb, 0.0f);
            }
        }
    }

    // ---- phase D: topk — per wave, 8 rows; g re-read from global (L2-hot,
    // written by this block in stage2; ordered by the stage-2->3 barrier) ----
#pragma unroll 1
    for (int jr = 0; jr < 8; ++jr) {
        const int r = wave * 8 + jr;
        const long bb = row0 + r;
        float gv[4];
#pragma unroll
        for (int i = 0; i < 4; ++i) gv[i] = g[bb * 256 + lane + 64 * i];

        float s = gv[0] + gv[1] + gv[2] + gv[3];
        float mx = fmaxf(fmaxf(gv[0], gv[1]), fmaxf(gv[2], gv[3]));
        for (int m = 32; m; m >>= 1) {
            s  += __shfl_xor(s, m);
            mx  = fmaxf(mx, __shfl_xor(mx, m));
        }
        const float mean = s * (1.0f / 256.0f);
        float vs = 0.0f;
#pragma unroll
        for (int i = 0; i < 4; ++i) { float d = gv[i] - mean; vs += d * d; }
        for (int m = 32; m; m >>= 1) vs += __shfl_xor(vs, m);
        const float stdv = sqrtf(vs * (1.0f / 256.0f));

        float cur[4]; int curi[4];
#pragma unroll
        for (int i = 0; i < 4; ++i) { cur[i] = gv[i]; curi[i] = lane + 64 * i; }
        float tv[KTOP]; int ti[KTOP]; float vsum = 0.0f;
#pragma unroll
        for (int rr = 0; rr < KTOP; ++rr) {
            float bv = cur[0]; int bi = curi[0];
#pragma unroll
            for (int i = 1; i < 4; ++i)
                if (cur[i] > bv || (cur[i] == bv && curi[i] < bi)) { bv = cur[i]; bi = curi[i]; }
            for (int m = 32; m; m >>= 1) {
                float ov = __shfl_xor(bv, m);
                int   oi = __shfl_xor(bi, m);
                if (ov > bv || (ov == bv && oi < bi)) { bv = ov; bi = oi; }
            }
            tv[rr] = bv; ti[rr] = bi; vsum += bv;
#pragma unroll
            for (int i = 0; i < 4; ++i) if (curi[i] == bi) cur[i] = -INFINITY;
        }
        const float denom = 1.0f / (vsum + 1e-6f);

        float hm = 0.0f;
        if (lane < 16) {
#pragma unroll
            for (int k = 0; k < KTOP; ++k) {
                const float xk = x_cal[bb * 256 + ti[k]];
                const float xw = xk * (tv[k] * denom);
                hm += fmaxf(xw * tw1[lane] + tb1[lane], 0.0f);
            }
            hm *= (1.0f / (float)KTOP);
        }
        if (lane < 16) {
            float z = tb2[lane];
#pragma unroll
            for (int j = 0; j < 16; ++j) z += __shfl(hm, j) * tw2[j * 16 + lane];
            z_top[bb * TS + lane] = z;
        }
        if (lane == 0) {
            stats[bb * 4 + 0] = mean;
            stats[bb * 4 + 1] = mx;
            stats[bb * 4 + 2] = stdv;
        }
    }
}

// ---------------------------------------------------------------------------
// k_tail3 (pkbf in packing loops)
// ---------------------------------------------------------------------------
static constexpr int HST = 260;
static constexpr int AST = 312;

template<int KP>
__device__ __forceinline__ void head_mfma16(
    const short* sa, const short* __restrict__ Wt,
    const float* __restrict__ b1v, const float* __restrict__ w2v, int Nreal,
    float (*s_red)[16], int wave, int sub, int quad)
{
    f32x4 acc[2];
#pragma unroll
    for (int t = 0; t < 2; ++t) acc[t] = (f32x4){0, 0, 0, 0};
#pragma unroll
    for (int k0 = 0; k0 < KP; k0 += 32) {
        const bf16x8 af = *reinterpret_cast<const bf16x8*>(
            &sa[sub * AST + k0 + quad * 8]);
#pragma unroll
        for (int t = 0; t < 2; ++t) {
            const int col = wave * 32 + t * 16 + sub;
            const bf16x8 bf = *reinterpret_cast<const bf16x8*>(
                &Wt[(long)col * KP + k0 + quad * 8]);
            acc[t] = __builtin_amdgcn_mfma_f32_16x16x32_bf16(af, bf, acc[t], 0, 0, 0);
        }
    }
    float rsum[4] = {0, 0, 0, 0};
#pragma unroll
    for (int t = 0; t < 2; ++t) {
        const int col = wave * 32 + t * 16 + sub;
        const float bb = (col < Nreal) ? b1v[col] : 0.0f;
        const float ww = (col < Nreal) ? w2v[col] : 0.0f;
#pragma unroll
        for (int rr = 0; rr < 4; ++rr)
            rsum[rr] += fmaxf(acc[t][rr] + bb, 0.0f) * ww;
    }
#pragma unroll
    for (int rr = 0; rr < 4; ++rr)
        for (int m = 1; m < 16; m <<= 1) rsum[rr] += __shfl_xor(rsum[rr], m);
    if (sub == 0) {
#pragma unroll
        for (int rr = 0; rr < 4; ++rr)
            s_red[wave][quad * 4 + rr] = rsum[rr];
    }
}

__global__ __launch_bounds__(256) void k_tail3(
    const float* __restrict__ h_base, const float* __restrict__ z_top,
    const float* __restrict__ gstats,
    const float* __restrict__ base_w, const float* __restrict__ base_b,
    const float* __restrict__ safe_lg, const float* __restrict__ safe_lb,
    const short* __restrict__ sw1t, const float* __restrict__ safe_b1,
    const float* __restrict__ safe_w2, const float* __restrict__ safe_b2,
    const float* __restrict__ spec_lg, const float* __restrict__ spec_lb,
    const short* __restrict__ spw1t, const float* __restrict__ spec_b1,
    const float* __restrict__ spec_w2, const float* __restrict__ spec_b2,
    const float* __restrict__ conf_lg, const float* __restrict__ conf_lb,
    const short* __restrict__ cfw1t, const float* __restrict__ conf_b1,
    const float* __restrict__ conf_w2, const float* __restrict__ conf_b2,
    float* __restrict__ out)
{
    __shared__ float s_h[16 * HST];
    __shared__ short s_a[16 * AST];
    __shared__ float s_z[16 * 16];
    __shared__ float s_g[16 * 4];
    __shared__ float s_sc[16 * 14];
    __shared__ float s_red[4][16];

    const int tid = threadIdx.x;
    const int wave = tid >> 6, lane = tid & 63;
    const int sub = lane & 15, quad = lane >> 4;
    const long row0 = (long)blockIdx.x * 16;

    for (int idx = tid; idx < 16 * 64; idx += 256) {
        const int r = idx >> 6, q = idx & 63;
        *reinterpret_cast<float4*>(&s_h[r * HST + q * 4]) =
            *reinterpret_cast<const float4*>(&h_base[(row0 + r) * 256 + q * 4]);
    }
    if (tid < 256) s_z[tid] = z_top[row0 * 16 + tid];
    if (tid < 64) s_g[tid] = gstats[row0 * 4 + tid];
    __syncthreads();

    {
        const int r = tid >> 4, l16 = tid & 15;
        float S = 0.0f, SS = 0.0f, Y = 0.0f;
#pragma unroll
        for (int i = 0; i < 16; ++i) {
            const int k = l16 + 16 * i;
            const float v = s_h[r * HST + k];
            S += v; SS += v * v; Y += v * base_w[k];
        }
        const float z0 = s_z[r * 16 + l16];
        float Sz = z0, SSz = z0 * z0;
#pragma unroll
        for (int m = 1; m < 16; m <<= 1) {
            S += __shfl_xor(S, m); SS += __shfl_xor(SS, m); Y += __shfl_xor(Y, m);
            Sz += __shfl_xor(Sz, m); SSz += __shfl_xor(SSz, m);
        }
        if (l16 == 0) {
            float* sc = &s_sc[r * 14];
            sc[0] = S; sc[1] = SS; sc[2] = Sz; sc[3] = SSz;
            sc[4] = Y + base_b[0];
            const float mu = S * (1.0f / 256.0f);
            sc[5] = mu;
            sc[6] = rsqrtf(SS * (1.0f / 256.0f) - mu * mu + 1e-5f);
            const float musp = (S + Sz) * (1.0f / (float)SPD);
            sc[7] = musp;
            sc[8] = rsqrtf((SS + SSz) * (1.0f / (float)SPD) - musp * musp + 1e-5f);
        }
    }
    __syncthreads();

    for (int idx = tid; idx < 16 * 128; idx += 256) {
        const int r = idx >> 7, k = (idx & 127) * 2;
        const float mu = s_sc[r * 14 + 5], rs = s_sc[r * 14 + 6];
        const float v0 = (s_h[r * HST + k] - mu) * rs * safe_lg[k] + safe_lb[k];
        const float v1 = (s_h[r * HST + k + 1] - mu) * rs * safe_lg[k + 1] + safe_lb[k + 1];
        *reinterpret_cast<unsigned*>(&s_a[r * AST + k]) = pkbf(v0, v1);
    }
    __syncthreads();

    head_mfma16<256>(s_a, sw1t, safe_b1, safe_w2, 128, s_red, wave, sub, quad);
    __syncthreads();

    if (tid < 16)
        s_sc[tid * 14 + 9] = s_red[0][tid] + s_red[1][tid] + s_red[2][tid] + s_red[3][tid] + safe_b2[0];
    for (int idx = tid; idx < 16 * 144; idx += 256) {
        const int r = idx / 144, k = (idx - r * 144) * 2;
        const float mu = s_sc[r * 14 + 7], rs = s_sc[r * 14 + 8];
        float vv[2];
#pragma unroll
        for (int h = 0; h < 2; ++h) {
            const int kk = k + h;
            float raw = (kk < 256) ? s_h[r * HST + kk]
                       : (kk < SPD) ? s_z[r * 16 + kk - 256] : 0.0f;
            vv[h] = (kk < SPD) ? (raw - mu) * rs * spec_lg[kk] + spec_lb[kk] : 0.0f;
        }
        *reinterpret_cast<unsigned*>(&s_a[r * AST + k]) = pkbf(vv[0], vv[1]);
    }
    __syncthreads();

    head_mfma16<288>(s_a, spw1t, spec_b1, spec_w2, SPH, s_red, wave, sub, quad);
    __syncthreads();

    if (tid < 16) {
        float* sc = &s_sc[tid * 14];
        const float dsp = s_red[0][tid] + s_red[1][tid] + s_red[2][tid] + s_red[3][tid] + spec_b2[0];
        sc[10] = dsp;
        const float yb = sc[4];
        const float gm = s_g[tid * 4 + 0], gx = s_g[tid * 4 + 1], gs = s_g[tid * 4 + 2];
        const float ads = fabsf(sc[9]), adp = fabsf(dsp);
        const float es = yb + gm + gx + gs + ads + adp;
        const float eq = yb * yb + gm * gm + gx * gx + gs * gs + ads * ads + adp * adp;
        const float muc = (sc[0] + sc[2] + es) * (1.0f / (float)CD);
        sc[11] = muc;
        sc[12] = rsqrtf((sc[1] + sc[3] + eq) * (1.0f / (float)CD) - muc * muc + 1e-5f);
    }
    __syncthreads();

    for (int idx = tid; idx < 16 * 144; idx += 256) {
        const int r = idx / 144, k = (idx - r * 144) * 2;
        const float mu = s_sc[r * 14 + 11], rs = s_sc[r * 14 + 12];
        float vv[2];
#pragma unroll
        for (int h = 0; h < 2; ++h) {
            const int kk = k + h;
            float raw;
            if (kk < 256)       raw = s_h[r * HST + kk];
            else if (kk == 256) raw = s_sc[r * 14 + 4];
            else if (kk == 257) raw = s_g[r * 4 + 0];
            else if (kk == 258) raw = s_g[r * 4 + 1];
            else if (kk == 259) raw = s_g[r * 4 + 2];
            else if (kk < 276)  raw = s_z[r * 16 + kk - 260];
            else if (kk == 276) raw = fabsf(s_sc[r * 14 + 9]);
            else if (kk == 277) raw = fabsf(s_sc[r * 14 + 10]);
            else                raw = 0.0f;
            vv[h] = (kk < CD) ? (raw - mu) * rs * conf_lg[kk] + conf_lb[kk] : 0.0f;
        }
        *reinterpret_cast<unsigned*>(&s_a[r * AST + k]) = pkbf(vv[0], vv[1]);
    }
    __syncthreads();

    head_mfma16<288>(s_a, cfw1t, conf_b1, conf_w2, CH, s_red, wave, sub, quad);
    __syncthreads();

    if (tid < 16) {
        const float* sc = &s_sc[tid * 14];
        const float gamma = 1.0f / (1.0f + __expf(
            -(s_red[0][tid] + s_red[1][tid] + s_red[2][tid] + s_red[3][tid] + conf_b2[0])));
        out[row0 + tid] = sc[4] + sc[9] + gamma * sc[10];
    }
}

// ---------------------------------------------------------------------------
extern "C" void kernel_launch(void* const* d_in, const int* in_sizes, int n_in,
                              void* d_out, int out_size, void* d_ws, size_t ws_size,
                              hipStream_t stream)
{
    const float* x_num   = (const float*)d_in[0];
    const float* center  = (const float*)d_in[1];
    const float* scale   = (const float*)d_in[2];
    const float* qs      = (const float*)d_in[3];
    const float* stem_w1 = (const float*)d_in[4];
    const float* stem_b1 = (const float*)d_in[5];
    const float* stem_w2 = (const float*)d_in[6];
    const float* stem_b2 = (const float*)d_in[7];
    const float* stem_w3 = (const float*)d_in[8];
    const float* stem_b3 = (const float*)d_in[9];
    const float* gate_w1 = (const float*)d_in[10];
    const float* gate_b1 = (const float*)d_in[11];
    const float* gate_w2 = (const float*)d_in[12];
    const float* gate_b2 = (const float*)d_in[13];
    const float* bb_w    = (const float*)d_in[14];
    const float* bb_b    = (const float*)d_in[15];
    const float* base_w  = (const float*)d_in[16];
    const float* base_b  = (const float*)d_in[17];
    const float* safe_lg = (const float*)d_in[18];
    const float* safe_lb = (const float*)d_in[19];
    const float* safe_w1 = (const float*)d_in[20];
    const float* safe_b1 = (const float*)d_in[21];
    const float* safe_w2 = (const float*)d_in[22];
    const float* safe_b2 = (const float*)d_in[23];
    const float* top_w1  = (const float*)d_in[24];
    const float* top_b1  = (const float*)d_in[25];
    const float* top_w2  = (const float*)d_in[26];
    const float* top_b2  = (const float*)d_in[27];
    const float* spec_lg = (const float*)d_in[28];
    const float* spec_lb = (const float*)d_in[29];
    const float* spec_w1 = (const float*)d_in[30];
    const float* spec_b1 = (const float*)d_in[31];
    const float* spec_w2 = (const float*)d_in[32];
    const float* spec_b2 = (const float*)d_in[33];
    const float* conf_lg = (const float*)d_in[34];
    const float* conf_lb = (const float*)d_in[35];
    const float* conf_w1 = (const float*)d_in[36];
    const float* conf_b1 = (const float*)d_in[37];
    const float* conf_w2 = (const float*)d_in[38];
    const float* conf_b2 = (const float*)d_in[39];

    float* ws    = (float*)d_ws;
    float* x_cal = ws;                         // B*256
    float* g_h   = x_cal + (long)B * 256;      // B*128 (unused, kept for layout)
    float* g     = g_h   + (long)B * 128;      // B*256
    float* h_b   = g     + (long)B * 256;      // B*256
    float* z_top = h_b   + (long)B * 256;      // B*16
    float* gstat = z_top + (long)B * 16;       // B*4
    short* w1t   = (short*)(gstat + (long)B * 4);  // 128*256
    short* w2t   = w1t   + 128 * 256;              // 256*128
    short* bbt   = w2t   + 256 * 128;              // 256*256
    short* sw1t  = bbt   + 256 * 256;              // 128*256
    short* spw1t = sw1t  + 128 * 256;              // 128*288
    short* cfw1t = spw1t + 128 * 288;              // 128*288
    unsigned* w2ph = (unsigned*)(cfw1t + 128 * 288);  // 128 u32 (f16 pairs)
    unsigned* w3ph = w2ph + 128;                      // 8 u32
    float* qs_t  = (float*)(w3ph + 8);                // 256*2048 f32 (own slot)
    float* out   = (float*)d_out;

    k_prepall<<<1057, 256, 0, stream>>>(gate_w1, gate_w2, bb_w, safe_w1, spec_w1,
                                        conf_w1, qs, stem_w2, stem_w3,
                                        w1t, w2t, bbt, sw1t, spw1t, cfw1t, qs_t,
                                        w2ph, w3ph);
    k_calib7<<<512, 256, 0, stream>>>(x_num, center, scale, qs, qs_t,
                                      stem_w1, stem_b1, w2ph, stem_b2, w3ph, stem_b3,
                                      x_cal);
    k_fused2<<<512, 256, 0, stream>>>(x_cal, w1t, gate_b1, w2t, gate_b2, bbt, bb_b,
                                      top_w1, top_b1, top_w2, top_b2,
                                      g, h_b, z_top, gstat);
    k_tail3<<<B / 16, 256, 0, stream>>>(h_b, z_top, gstat,
                                        base_w, base_b,
                                        safe_lg, safe_lb, sw1t, safe_b1, safe_w2, safe_b2,
                                        spec_lg, spec_lb, spw1t, spec_b1, spec_w2, spec_b2,
                                        conf_lg, conf_lb, cfw1t, conf_b1, conf_w2, conf_b2,
                                        out);
}

// Round 15
// 304.835 us; speedup vs baseline: 1.0595x; 1.0595x over previous
//
#include <hip/hip_runtime.h>
#include <hip/hip_bf16.h>
#include <math.h>

static constexpr int B  = 16384;
static constexpr int F  = 256;
static constexpr int NQ = 2048;
static constexpr int TS = 16;
static constexpr int KTOP = 8;
static constexpr int SPD = 272;   // 256 + 16
static constexpr int SPH = 68;
static constexpr int CD  = 278;   // 256+1+3+16+2
static constexpr int CH  = 69;

typedef __attribute__((ext_vector_type(8))) short bf16x8;
typedef __attribute__((ext_vector_type(4))) float f32x4;
typedef _Float16 f16x2 __attribute__((ext_vector_type(2)));
typedef unsigned u32x4 __attribute__((ext_vector_type(4)));

__device__ inline short f2bf(float f) {
    unsigned u = __builtin_bit_cast(unsigned, f);
    unsigned r = (u + 0x7FFF + ((u >> 16) & 1)) >> 16;   // RNE
    return (short)r;
}

// packed f32x2 -> bf16x2 (RNE), single v_cvt_pk_bf16_f32
__device__ inline unsigned pkbf(float a, float b) {
    __hip_bfloat162 h = __float22bfloat162_rn(make_float2(a, b));
    unsigned u;
    __builtin_memcpy(&u, &h, 4);
    return u;
}

__device__ inline float fast_tanh(float o) {
    o = fminf(fmaxf(o, -15.0f), 15.0f);
    float e = __expf(2.0f * o);
    return (e - 1.0f) / (e + 1.0f);
}

// cvt_pkrtz returns __fp16x2; fdot2 wants _Float16x2 — bit-identical, shim it.
__device__ inline f16x2 cvt2h(float a, float b) {
    return __builtin_bit_cast(f16x2, __builtin_amdgcn_cvt_pkrtz(a, b));
}

__device__ inline unsigned pack2h(float a, float b) {
    return __builtin_bit_cast(unsigned, __builtin_amdgcn_cvt_pkrtz(a, b));
}

// ---------------------------------------------------------------------------
// k_prepall: bf16 W^T buffers (padded) + f16-pair stem weights (blocks 0..928)
// + LDS-tiled COALESCED qs transpose (blocks 929..1056, 64x64 tiles).
// ---------------------------------------------------------------------------
__device__ inline void prep_one(const float* W, short* T, int local,
                                int K, int N, int KP) {
    const int n = local / KP, k = local - n * KP;
    T[local] = (k < K && n < N) ? f2bf(W[k * N + n]) : (short)0;
}

__global__ __launch_bounds__(256) void k_prepall(
    const float* __restrict__ gate_w1, const float* __restrict__ gate_w2,
    const float* __restrict__ bb_w,    const float* __restrict__ safe_w1,
    const float* __restrict__ spec_w1, const float* __restrict__ conf_w1,
    const float* __restrict__ qs,
    const float* __restrict__ stem_w2, const float* __restrict__ stem_w3,
    short* __restrict__ w1t, short* __restrict__ w2t, short* __restrict__ bbt,
    short* __restrict__ sw1t, short* __restrict__ spw1t, short* __restrict__ cfw1t,
    float* __restrict__ qs_t,
    unsigned* __restrict__ w2ph, unsigned* __restrict__ w3ph)
{
    __shared__ float tile[64][65];
    if (blockIdx.x < 929) {
        const int idx = blockIdx.x * 256 + threadIdx.x;
        if (idx < 32768)       prep_one(gate_w1, w1t,  idx,           256, 128, 256);
        else if (idx < 65536)  prep_one(gate_w2, w2t,  idx - 32768,   128, 256, 128);
        else if (idx < 131072) prep_one(bb_w,    bbt,  idx - 65536,   256, 256, 256);
        else if (idx < 163840) prep_one(safe_w1, sw1t, idx - 131072,  256, 128, 256);
        else if (idx < 200704) prep_one(spec_w1, spw1t, idx - 163840, 272, 68, 288);
        else if (idx < 237568) prep_one(conf_w1, cfw1t, idx - 200704, 278, 69, 288);
        else if (idx < 237696) {
            // stem_w2 packed as f16 pairs along K
            const int l = idx - 237568;            // 0..127
            const int t = l >> 4, j = l & 15;
            w2ph[l] = pack2h(stem_w2[(2 * t) * 16 + j], stem_w2[(2 * t + 1) * 16 + j]);
        }
        else if (idx < 237704) {
            const int u = idx - 237696;            // 0..7
            w3ph[u] = pack2h(stem_w3[2 * u], stem_w3[2 * u + 1]);
        }
    } else {
        // 64x64 tile transpose: qs [2048][256] -> qs_t [256][2048]
        const int t = blockIdx.x - 929;            // 0..127
        const int tq = t & 31, tf = t >> 5;        // 32 q-tiles x 4 f-tiles
        const int q0 = tq * 64, f0 = tf * 64;
        const int c = threadIdx.x & 63, r4 = threadIdx.x >> 6;
#pragma unroll
        for (int rr = 0; rr < 16; ++rr) {
            const int row = rr * 4 + r4;
            tile[row][c] = qs[(q0 + row) * 256 + f0 + c];   // coalesced in f
        }
        __syncthreads();
#pragma unroll
        for (int rr = 0; rr < 16; ++rr) {
            const int fr = rr * 4 + r4;
            qs_t[(long)(f0 + fr) * 2048 + q0 + c] = tile[c][fr];  // coalesced in q
        }
    }
}

// ---------------------------------------------------------------------------
// k_calib7: thread = feature, 32 rows/block (grid 512) — measured-best
// structure: pipelined table fill, 6-level LDS binary search, 8-wide
// batching (`#pragma unroll 1` on the group loop), dot2-f16 stem MLP,
// x_num cross-group prefetch.
// ---------------------------------------------------------------------------
__global__ __launch_bounds__(256) void k_calib7(
    const float* __restrict__ x_num, const float* __restrict__ center,
    const float* __restrict__ scale, const float* __restrict__ qs,
    const float* __restrict__ qs_t,
    const float* __restrict__ sw1, const float* __restrict__ sb1,
    const unsigned* __restrict__ w2ph, const float* __restrict__ sb2,
    const unsigned* __restrict__ w3ph, const float* __restrict__ sb3,
    float* __restrict__ x_cal)
{
    __shared__ float cq[63 * 256];          // 63 KB
    const int tid = threadIdx.x;
    const int f = tid;
    // pipelined fill: 7 rounds of 9 independent loads
#pragma unroll 1
    for (int j0 = 0; j0 < 63; j0 += 9) {
        float t[9];
#pragma unroll
        for (int u = 0; u < 9; ++u) t[u] = qs[(32 * (j0 + u + 1)) * 256 + tid];
#pragma unroll
        for (int u = 0; u < 9; ++u) cq[(j0 + u) * 256 + tid] = t[u];
    }
    __syncthreads();

    const float c = center[f];
    const float inv_sc = 1.0f / scale[f];
    const float* colp = qs_t + (long)f * NQ;
    const long row_base = (long)blockIdx.x * 32;

    // prefetch group 0
    float xb[8];
#pragma unroll
    for (int i = 0; i < 8; ++i) xb[i] = x_num[(row_base + i) * F + f];

#pragma unroll 1
    for (int grp = 0; grp < 4; ++grp) {
        const long r0 = row_base + grp * 8;
        float x[8], xr[8];
#pragma unroll
        for (int i = 0; i < 8; ++i) x[i] = xb[i];
        // prefetch next group's x while this group computes
        if (grp < 3) {
#pragma unroll
            for (int i = 0; i < 8; ++i) xb[i] = x_num[(r0 + 8 + i) * F + f];
        }
#pragma unroll
        for (int i = 0; i < 8; ++i) xr[i] = (x[i] - c) * inv_sc;

        // coarse: 6-level binary search over 63 LDS boundaries
        int lo[8], hi[8];
#pragma unroll
        for (int i = 0; i < 8; ++i) { lo[i] = 0; hi[i] = 63; }
#pragma unroll
        for (int it = 0; it < 6; ++it) {
            float qv[8]; int mid[8];
#pragma unroll
            for (int i = 0; i < 8; ++i) {
                mid[i] = (lo[i] + hi[i]) >> 1;
                qv[i] = cq[mid[i] * 256 + f];
            }
#pragma unroll
            for (int i = 0; i < 8; ++i) {
                if (qv[i] < x[i]) lo[i] = mid[i] + 1; else hi[i] = mid[i];
            }
        }
        // probe mid of 32-window -> 16-half
        int base[8];
        {
            float pm[8];
#pragma unroll
            for (int i = 0; i < 8; ++i) pm[i] = colp[lo[i] * 32 + 16];
#pragma unroll
            for (int i = 0; i < 8; ++i)
                base[i] = lo[i] * 32 + ((pm[i] < x[i]) ? 16 : 0);
        }
        // one aligned 64B line: 4x float4, count < x
        float xq[8];
#pragma unroll
        for (int i = 0; i < 8; ++i) {
            const float4* wp = reinterpret_cast<const float4*>(&colp[base[i]]);
            const float4 a = wp[0], b = wp[1], d = wp[2], e = wp[3];
            int cN = 0;
            cN += (a.x < x[i]); cN += (a.y < x[i]); cN += (a.z < x[i]); cN += (a.w < x[i]);
            cN += (b.x < x[i]); cN += (b.y < x[i]); cN += (b.z < x[i]); cN += (b.w < x[i]);
            cN += (d.x < x[i]); cN += (d.y < x[i]); cN += (d.z < x[i]); cN += (d.w < x[i]);
            cN += (e.x < x[i]); cN += (e.y < x[i]); cN += (e.z < x[i]); cN += (e.w < x[i]);
            const int rank = base[i] + cN;
            xq[i] = fminf((float)rank * (1.0f / (float)(NQ - 1)), 1.0f);
        }

        // stem MLP: two sub-groups of 4 rows (register pressure);
        // h2 and output layer via v_dot2_f32_f16 (f32 accumulate)
#pragma unroll
        for (int hgrp = 0; hgrp < 2; ++hgrp) {
            const int o4 = hgrp * 4;
            float h2[4][16];
#pragma unroll
            for (int j = 0; j < 16; ++j) {
                const float bb = sb2[j];
#pragma unroll
                for (int i = 0; i < 4; ++i) h2[i][j] = bb;
            }
#pragma unroll 4
            for (int t = 0; t < 8; ++t) {
                const float w0a = sw1[2 * t],     w1a = sw1[16 + 2 * t],     w2a = sw1[32 + 2 * t];
                const float w0b = sw1[2 * t + 1], w1b = sw1[16 + 2 * t + 1], w2b = sw1[32 + 2 * t + 1];
                const float ba = sb1[2 * t], bbv = sb1[2 * t + 1];
                f16x2 hp[4];
#pragma unroll
                for (int i = 0; i < 4; ++i) {
                    const float ha = fmaxf(ba  + x[o4 + i] * w0a + xr[o4 + i] * w1a + xq[o4 + i] * w2a, 0.0f);
                    const float hb = fmaxf(bbv + x[o4 + i] * w0b + xr[o4 + i] * w1b + xq[o4 + i] * w2b, 0.0f);
                    hp[i] = cvt2h(ha, hb);
                }
                unsigned ww[16];
                const uint4* wr = reinterpret_cast<const uint4*>(&w2ph[t * 16]);
                *reinterpret_cast<uint4*>(&ww[0])  = wr[0];
                *reinterpret_cast<uint4*>(&ww[4])  = wr[1];
                *reinterpret_cast<uint4*>(&ww[8])  = wr[2];
                *reinterpret_cast<uint4*>(&ww[12]) = wr[3];
#pragma unroll
                for (int j = 0; j < 16; ++j) {
                    const f16x2 wj = __builtin_bit_cast(f16x2, ww[j]);
#pragma unroll
                    for (int i = 0; i < 4; ++i)
                        h2[i][j] = __builtin_amdgcn_fdot2(hp[i], wj, h2[i][j], false);
                }
            }
            const float b3 = sb3[0];
            float o[4] = {b3, b3, b3, b3};
#pragma unroll
            for (int u = 0; u < 8; ++u) {
                const f16x2 wu = __builtin_bit_cast(f16x2, w3ph[u]);
#pragma unroll
                for (int i = 0; i < 4; ++i) {
                    const f16x2 hh = cvt2h(
                        fmaxf(h2[i][2 * u], 0.0f), fmaxf(h2[i][2 * u + 1], 0.0f));
                    o[i] = __builtin_amdgcn_fdot2(hh, wu, o[i], false);
                }
            }
#pragma unroll
            for (int i = 0; i < 4; ++i)
                x_cal[(r0 + o4 + i) * F + f] = x[o4 + i] + 0.1f * fast_tanh(o[i]);
        }
    }
}

// ---------------------------------------------------------------------------
// k_fused: gate1 (256->128 relu) -> gate2 (128->256 sigmoid, writes g) ->
//          backbone (x_cal*g, 256->256 relu, writes h_b). 32 rows/block.
// ---------------------------------------------------------------------------
static constexpr int ST1 = 136;   // bf16 stride for h1 (32x128)
static constexpr int ST2 = 264;   // bf16 stride for x_gated (32x256)

__global__ __launch_bounds__(256) void k_fused(
    const float* __restrict__ x_cal,
    const short* __restrict__ w1t, const float* __restrict__ gate_b1,
    const short* __restrict__ w2t, const float* __restrict__ gate_b2,
    const short* __restrict__ bbt, const float* __restrict__ bb_b,
    float* __restrict__ g, float* __restrict__ h_b)
{
    __shared__ short s_c1[32 * ST1];
    __shared__ short s_xg[32 * ST2];

    const int tid = threadIdx.x;
    const int wave = tid >> 6, lane = tid & 63;
    const int sub = lane & 15, quad = lane >> 4;
    const int wm = wave & 1, wn = wave >> 1;
    const long row0 = (long)blockIdx.x * 32;
    const long mrow = row0 + wm * 16 + sub;

    // ---- stage1: h1 = relu(x_cal @ W1 + b1), 32x128 ----
    {
        f32x4 acc[4];
#pragma unroll
        for (int t = 0; t < 4; ++t) acc[t] = (f32x4){0, 0, 0, 0};
#pragma unroll
        for (int k0 = 0; k0 < 256; k0 += 32) {
            const float* ap = x_cal + mrow * 256 + k0 + quad * 8;
            float av[8];
            *reinterpret_cast<float4*>(&av[0]) = *reinterpret_cast<const float4*>(ap);
            *reinterpret_cast<float4*>(&av[4]) = *reinterpret_cast<const float4*>(ap + 4);
            u32x4 afu;
            afu[0] = pkbf(av[0], av[1]);
            afu[1] = pkbf(av[2], av[3]);
            afu[2] = pkbf(av[4], av[5]);
            afu[3] = pkbf(av[6], av[7]);
            const bf16x8 af = __builtin_bit_cast(bf16x8, afu);
#pragma unroll
            for (int t = 0; t < 4; ++t) {
                const int col = wn * 64 + t * 16 + sub;
                const bf16x8 bf = *reinterpret_cast<const bf16x8*>(
                    &w1t[(long)col * 256 + k0 + quad * 8]);
                acc[t] = __builtin_amdgcn_mfma_f32_16x16x32_bf16(af, bf, acc[t], 0, 0, 0);
            }
        }
#pragma unroll
        for (int t = 0; t < 4; ++t) {
            const int col = wn * 64 + t * 16 + sub;
            const float bb = gate_b1[col];
#pragma unroll
            for (int r = 0; r < 4; ++r) {
                const int rowl = wm * 16 + quad * 4 + r;
                s_c1[rowl * ST1 + col] = f2bf(fmaxf(acc[t][r] + bb, 0.0f));
            }
        }
    }
    __syncthreads();

    // ---- stage2: g = sigmoid(h1 @ W2 + b2), 32x256; build x_gated bf16 ----
    {
        f32x4 acc[8];
#pragma unroll
        for (int t = 0; t < 8; ++t) acc[t] = (f32x4){0, 0, 0, 0};
#pragma unroll
        for (int k0 = 0; k0 < 128; k0 += 32) {
            const bf16x8 af = *reinterpret_cast<const bf16x8*>(
                &s_c1[(wm * 16 + sub) * ST1 + k0 + quad * 8]);
#pragma unroll
            for (int t = 0; t < 8; ++t) {
                const int col = wn * 128 + t * 16 + sub;
                const bf16x8 bf = *reinterpret_cast<const bf16x8*>(
                    &w2t[(long)col * 128 + k0 + quad * 8]);
                acc[t] = __builtin_amdgcn_mfma_f32_16x16x32_bf16(af, bf, acc[t], 0, 0, 0);
            }
        }
#pragma unroll
        for (int t = 0; t < 8; ++t) {
            const int col = wn * 128 + t * 16 + sub;
            const float bb = gate_b2[col];
#pragma unroll
            for (int r = 0; r < 4; ++r) {
                const int rowl = wm * 16 + quad * 4 + r;
                const float gv = 1.0f / (1.0f + __expf(-(acc[t][r] + bb)));
                g[(row0 + rowl) * 256 + col] = gv;
                const float xg = x_cal[(row0 + rowl) * 256 + col] * gv;
                s_xg[rowl * ST2 + col] = f2bf(xg);
            }
        }
    }
    __syncthreads();

    // ---- stage3: h_b = relu(x_gated @ BB + bb_b), 32x256 ----
    {
        f32x4 acc[8];
#pragma unroll
        for (int t = 0; t < 8; ++t) acc[t] = (f32x4){0, 0, 0, 0};
#pragma unroll
        for (int k0 = 0; k0 < 256; k0 += 32) {
            const bf16x8 af = *reinterpret_cast<const bf16x8*>(
                &s_xg[(wm * 16 + sub) * ST2 + k0 + quad * 8]);
#pragma unroll
            for (int t = 0; t < 8; ++t) {
                const int col = wn * 128 + t * 16 + sub;
                const bf16x8 bf = *reinterpret_cast<const bf16x8*>(
                    &bbt[(long)col * 256 + k0 + quad * 8]);
                acc[t] = __builtin_amdgcn_mfma_f32_16x16x32_bf16(af, bf, acc[t], 0, 0, 0);
            }
        }
#pragma unroll
        for (int t = 0; t < 8; ++t) {
            const int col = wn * 128 + t * 16 + sub;
            const float bb = bb_b[col];
#pragma unroll
            for (int r = 0; r < 4; ++r) {
                const int rowl = wm * 16 + quad * 4 + r;
                h_b[(row0 + rowl) * 256 + col] = fmaxf(acc[t][r] + bb, 0.0f);
            }
        }
    }
}

// ---------------------------------------------------------------------------
// k_topk: 4 batches per block (wave w handles b = blockIdx.x*4 + w)
// ---------------------------------------------------------------------------
__global__ __launch_bounds__(256) void k_topk(
    const float* __restrict__ g, const float* __restrict__ x_cal,
    const float* __restrict__ tw1, const float* __restrict__ tb1,
    const float* __restrict__ tw2, const float* __restrict__ tb2,
    float* __restrict__ z_top, float* __restrict__ stats)
{
    __shared__ float s_hm[4][16];
    const int wave = threadIdx.x >> 6;
    const int lane = threadIdx.x & 63;
    const int b = blockIdx.x * 4 + wave;
    const long base = (long)b * F;

    float gv[4];
#pragma unroll
    for (int i = 0; i < 4; ++i) gv[i] = g[base + lane + 64 * i];

    float s = gv[0] + gv[1] + gv[2] + gv[3];
    float mx = fmaxf(fmaxf(gv[0], gv[1]), fmaxf(gv[2], gv[3]));
    for (int m = 32; m; m >>= 1) {
        s  += __shfl_xor(s, m);
        mx  = fmaxf(mx, __shfl_xor(mx, m));
    }
    const float mean = s * (1.0f / 256.0f);
    float vs = 0.0f;
#pragma unroll
    for (int i = 0; i < 4; ++i) { float d = gv[i] - mean; vs += d * d; }
    for (int m = 32; m; m >>= 1) vs += __shfl_xor(vs, m);
    const float stdv = sqrtf(vs * (1.0f / 256.0f));

    float cur[4]; int curi[4];
#pragma unroll
    for (int i = 0; i < 4; ++i) { cur[i] = gv[i]; curi[i] = lane + 64 * i; }
    float tv[KTOP]; int ti[KTOP]; float vsum = 0.0f;
    for (int r = 0; r < KTOP; ++r) {
        float bv = cur[0]; int bi = curi[0];
#pragma unroll
        for (int i = 1; i < 4; ++i)
            if (cur[i] > bv || (cur[i] == bv && curi[i] < bi)) { bv = cur[i]; bi = curi[i]; }
        for (int m = 32; m; m >>= 1) {
            float ov = __shfl_xor(bv, m);
            int   oi = __shfl_xor(bi, m);
            if (ov > bv || (ov == bv && oi < bi)) { bv = ov; bi = oi; }
        }
        tv[r] = bv; ti[r] = bi; vsum += bv;
#pragma unroll
        for (int i = 0; i < 4; ++i) if (curi[i] == bi) cur[i] = -INFINITY;
    }
    const float denom = 1.0f / (vsum + 1e-6f);

    if (lane < 16) {
        float hm = 0.0f;
        for (int k = 0; k < KTOP; ++k) {
            const float xk = x_cal[base + ti[k]];
            const float xw = xk * (tv[k] * denom);
            hm += fmaxf(xw * tw1[lane] + tb1[lane], 0.0f);
        }
        s_hm[wave][lane] = hm * (1.0f / (float)KTOP);
    }
    __syncthreads();
    if (lane < 16) {
        float z = tb2[lane];
#pragma unroll
        for (int j = 0; j < 16; ++j) z += s_hm[wave][j] * tw2[j * 16 + lane];
        z_top[(long)b * TS + lane] = z;
    }
    if (lane == 0) {
        stats[(long)b * 4 + 0] = mean;
        stats[(long)b * 4 + 1] = mx;
        stats[(long)b * 4 + 2] = stdv;
    }
}

// ---------------------------------------------------------------------------
// k_tail3 (pkbf in packing loops)
// ---------------------------------------------------------------------------
static constexpr int HST = 260;
static constexpr int AST = 312;

template<int KP>
__device__ __forceinline__ void head_mfma16(
    const short* sa, const short* __restrict__ Wt,
    const float* __restrict__ b1v, const float* __restrict__ w2v, int Nreal,
    float (*s_red)[16], int wave, int sub, int quad)
{
    f32x4 acc[2];
#pragma unroll
    for (int t = 0; t < 2; ++t) acc[t] = (f32x4){0, 0, 0, 0};
#pragma unroll
    for (int k0 = 0; k0 < KP; k0 += 32) {
        const bf16x8 af = *reinterpret_cast<const bf16x8*>(
            &sa[sub * AST + k0 + quad * 8]);
#pragma unroll
        for (int t = 0; t < 2; ++t) {
            const int col = wave * 32 + t * 16 + sub;
            const bf16x8 bf = *reinterpret_cast<const bf16x8*>(
                &Wt[(long)col * KP + k0 + quad * 8]);
            acc[t] = __builtin_amdgcn_mfma_f32_16x16x32_bf16(af, bf, acc[t], 0, 0, 0);
        }
    }
    float rsum[4] = {0, 0, 0, 0};
#pragma unroll
    for (int t = 0; t < 2; ++t) {
        const int col = wave * 32 + t * 16 + sub;
        const float bb = (col < Nreal) ? b1v[col] : 0.0f;
        const float ww = (col < Nreal) ? w2v[col] : 0.0f;
#pragma unroll
        for (int rr = 0; rr < 4; ++rr)
            rsum[rr] += fmaxf(acc[t][rr] + bb, 0.0f) * ww;
    }
#pragma unroll
    for (int rr = 0; rr < 4; ++rr)
        for (int m = 1; m < 16; m <<= 1) rsum[rr] += __shfl_xor(rsum[rr], m);
    if (sub == 0) {
#pragma unroll
        for (int rr = 0; rr < 4; ++rr)
            s_red[wave][quad * 4 + rr] = rsum[rr];
    }
}

__global__ __launch_bounds__(256) void k_tail3(
    const float* __restrict__ h_base, const float* __restrict__ z_top,
    const float* __restrict__ gstats,
    const float* __restrict__ base_w, const float* __restrict__ base_b,
    const float* __restrict__ safe_lg, const float* __restrict__ safe_lb,
    const short* __restrict__ sw1t, const float* __restrict__ safe_b1,
    const float* __restrict__ safe_w2, const float* __restrict__ safe_b2,
    const float* __restrict__ spec_lg, const float* __restrict__ spec_lb,
    const short* __restrict__ spw1t, const float* __restrict__ spec_b1,
    const float* __restrict__ spec_w2, const float* __restrict__ spec_b2,
    const float* __restrict__ conf_lg, const float* __restrict__ conf_lb,
    const short* __restrict__ cfw1t, const float* __restrict__ conf_b1,
    const float* __restrict__ conf_w2, const float* __restrict__ conf_b2,
    float* __restrict__ out)
{
    __shared__ float s_h[16 * HST];
    __shared__ short s_a[16 * AST];
    __shared__ float s_z[16 * 16];
    __shared__ float s_g[16 * 4];
    __shared__ float s_sc[16 * 14];
    __shared__ float s_red[4][16];

    const int tid = threadIdx.x;
    const int wave = tid >> 6, lane = tid & 63;
    const int sub = lane & 15, quad = lane >> 4;
    const long row0 = (long)blockIdx.x * 16;

    for (int idx = tid; idx < 16 * 64; idx += 256) {
        const int r = idx >> 6, q = idx & 63;
        *reinterpret_cast<float4*>(&s_h[r * HST + q * 4]) =
            *reinterpret_cast<const float4*>(&h_base[(row0 + r) * 256 + q * 4]);
    }
    if (tid < 256) s_z[tid] = z_top[row0 * 16 + tid];
    if (tid < 64) s_g[tid] = gstats[row0 * 4 + tid];
    __syncthreads();

    {
        const int r = tid >> 4, l16 = tid & 15;
        float S = 0.0f, SS = 0.0f, Y = 0.0f;
#pragma unroll
        for (int i = 0; i < 16; ++i) {
            const int k = l16 + 16 * i;
            const float v = s_h[r * HST + k];
            S += v; SS += v * v; Y += v * base_w[k];
        }
        const float z0 = s_z[r * 16 + l16];
        float Sz = z0, SSz = z0 * z0;
#pragma unroll
        for (int m = 1; m < 16; m <<= 1) {
            S += __shfl_xor(S, m); SS += __shfl_xor(SS, m); Y += __shfl_xor(Y, m);
            Sz += __shfl_xor(Sz, m); SSz += __shfl_xor(SSz, m);
        }
        if (l16 == 0) {
            float* sc = &s_sc[r * 14];
            sc[0] = S; sc[1] = SS; sc[2] = Sz; sc[3] = SSz;
            sc[4] = Y + base_b[0];
            const float mu = S * (1.0f / 256.0f);
            sc[5] = mu;
            sc[6] = rsqrtf(SS * (1.0f / 256.0f) - mu * mu + 1e-5f);
            const float musp = (S + Sz) * (1.0f / (float)SPD);
            sc[7] = musp;
            sc[8] = rsqrtf((SS + SSz) * (1.0f / (float)SPD) - musp * musp + 1e-5f);
        }
    }
    __syncthreads();

    for (int idx = tid; idx < 16 * 128; idx += 256) {
        const int r = idx >> 7, k = (idx & 127) * 2;
        const float mu = s_sc[r * 14 + 5], rs = s_sc[r * 14 + 6];
        const float v0 = (s_h[r * HST + k] - mu) * rs * safe_lg[k] + safe_lb[k];
        const float v1 = (s_h[r * HST + k + 1] - mu) * rs * safe_lg[k + 1] + safe_lb[k + 1];
        *reinterpret_cast<unsigned*>(&s_a[r * AST + k]) = pkbf(v0, v1);
    }
    __syncthreads();

    head_mfma16<256>(s_a, sw1t, safe_b1, safe_w2, 128, s_red, wave, sub, quad);
    __syncthreads();

    if (tid < 16)
        s_sc[tid * 14 + 9] = s_red[0][tid] + s_red[1][tid] + s_red[2][tid] + s_red[3][tid] + safe_b2[0];
    for (int idx = tid; idx < 16 * 144; idx += 256) {
        const int r = idx / 144, k = (idx - r * 144) * 2;
        const float mu = s_sc[r * 14 + 7], rs = s_sc[r * 14 + 8];
        float vv[2];
#pragma unroll
        for (int h = 0; h < 2; ++h) {
            const int kk = k + h;
            float raw = (kk < 256) ? s_h[r * HST + kk]
                       : (kk < SPD) ? s_z[r * 16 + kk - 256] : 0.0f;
            vv[h] = (kk < SPD) ? (raw - mu) * rs * spec_lg[kk] + spec_lb[kk] : 0.0f;
        }
        *reinterpret_cast<unsigned*>(&s_a[r * AST + k]) = pkbf(vv[0], vv[1]);
    }
    __syncthreads();

    head_mfma16<288>(s_a, spw1t, spec_b1, spec_w2, SPH, s_red, wave, sub, quad);
    __syncthreads();

    if (tid < 16) {
        float* sc = &s_sc[tid * 14];
        const float dsp = s_red[0][tid] + s_red[1][tid] + s_red[2][tid] + s_red[3][tid] + spec_b2[0];
        sc[10] = dsp;
        const float yb = sc[4];
        const float gm = s_g[tid * 4 + 0], gx = s_g[tid * 4 + 1], gs = s_g[tid * 4 + 2];
        const float ads = fabsf(sc[9]), adp = fabsf(dsp);
        const float es = yb + gm + gx + gs + ads + adp;
        const float eq = yb * yb + gm * gm + gx * gx + gs * gs + ads * ads + adp * adp;
        const float muc = (sc[0] + sc[2] + es) * (1.0f / (float)CD);
        sc[11] = muc;
        sc[12] = rsqrtf((sc[1] + sc[3] + eq) * (1.0f / (float)CD) - muc * muc + 1e-5f);
    }
    __syncthreads();

    for (int idx = tid; idx < 16 * 144; idx += 256) {
        const int r = idx / 144, k = (idx - r * 144) * 2;
        const float mu = s_sc[r * 14 + 11], rs = s_sc[r * 14 + 12];
        float vv[2];
#pragma unroll
        for (int h = 0; h < 2; ++h) {
            const int kk = k + h;
            float raw;
            if (kk < 256)       raw = s_h[r * HST + kk];
            else if (kk == 256) raw = s_sc[r * 14 + 4];
            else if (kk == 257) raw = s_g[r * 4 + 0];
            else if (kk == 258) raw = s_g[r * 4 + 1];
            else if (kk == 259) raw = s_g[r * 4 + 2];
            else if (kk < 276)  raw = s_z[r * 16 + kk - 260];
            else if (kk == 276) raw = fabsf(s_sc[r * 14 + 9]);
            else if (kk == 277) raw = fabsf(s_sc[r * 14 + 10]);
            else                raw = 0.0f;
            vv[h] = (kk < CD) ? (raw - mu) * rs * conf_lg[kk] + conf_lb[kk] : 0.0f;
        }
        *reinterpret_cast<unsigned*>(&s_a[r * AST + k]) = pkbf(vv[0], vv[1]);
    }
    __syncthreads();

    head_mfma16<288>(s_a, cfw1t, conf_b1, conf_w2, CH, s_red, wave, sub, quad);
    __syncthreads();

    if (tid < 16) {
        const float* sc = &s_sc[tid * 14];
        const float gamma = 1.0f / (1.0f + __expf(
            -(s_red[0][tid] + s_red[1][tid] + s_red[2][tid] + s_red[3][tid] + conf_b2[0])));
        out[row0 + tid] = sc[4] + sc[9] + gamma * sc[10];
    }
}

// ---------------------------------------------------------------------------
extern "C" void kernel_launch(void* const* d_in, const int* in_sizes, int n_in,
                              void* d_out, int out_size, void* d_ws, size_t ws_size,
                              hipStream_t stream)
{
    const float* x_num   = (const float*)d_in[0];
    const float* center  = (const float*)d_in[1];
    const float* scale   = (const float*)d_in[2];
    const float* qs      = (const float*)d_in[3];
    const float* stem_w1 = (const float*)d_in[4];
    const float* stem_b1 = (const float*)d_in[5];
    const float* stem_w2 = (const float*)d_in[6];
    const float* stem_b2 = (const float*)d_in[7];
    const float* stem_w3 = (const float*)d_in[8];
    const float* stem_b3 = (const float*)d_in[9];
    const float* gate_w1 = (const float*)d_in[10];
    const float* gate_b1 = (const float*)d_in[11];
    const float* gate_w2 = (const float*)d_in[12];
    const float* gate_b2 = (const float*)d_in[13];
    const float* bb_w    = (const float*)d_in[14];
    const float* bb_b    = (const float*)d_in[15];
    const float* base_w  = (const float*)d_in[16];
    const float* base_b  = (const float*)d_in[17];
    const float* safe_lg = (const float*)d_in[18];
    const float* safe_lb = (const float*)d_in[19];
    const float* safe_w1 = (const float*)d_in[20];
    const float* safe_b1 = (const float*)d_in[21];
    const float* safe_w2 = (const float*)d_in[22];
    const float* safe_b2 = (const float*)d_in[23];
    const float* top_w1  = (const float*)d_in[24];
    const float* top_b1  = (const float*)d_in[25];
    const float* top_w2  = (const float*)d_in[26];
    const float* top_b2  = (const float*)d_in[27];
    const float* spec_lg = (const float*)d_in[28];
    const float* spec_lb = (const float*)d_in[29];
    const float* spec_w1 = (const float*)d_in[30];
    const float* spec_b1 = (const float*)d_in[31];
    const float* spec_w2 = (const float*)d_in[32];
    const float* spec_b2 = (const float*)d_in[33];
    const float* conf_lg = (const float*)d_in[34];
    const float* conf_lb = (const float*)d_in[35];
    const float* conf_w1 = (const float*)d_in[36];
    const float* conf_b1 = (const float*)d_in[37];
    const float* conf_w2 = (const float*)d_in[38];
    const float* conf_b2 = (const float*)d_in[39];

    float* ws    = (float*)d_ws;
    float* x_cal = ws;                         // B*256
    float* g_h   = x_cal + (long)B * 256;      // B*128 (unused, kept for layout)
    float* g     = g_h   + (long)B * 128;      // B*256
    float* h_b   = g     + (long)B * 256;      // B*256
    float* z_top = h_b   + (long)B * 256;      // B*16
    float* gstat = z_top + (long)B * 16;       // B*4
    short* w1t   = (short*)(gstat + (long)B * 4);  // 128*256
    short* w2t   = w1t   + 128 * 256;              // 256*128
    short* bbt   = w2t   + 256 * 128;              // 256*256
    short* sw1t  = bbt   + 256 * 256;              // 128*256
    short* spw1t = sw1t  + 128 * 256;              // 128*288
    short* cfw1t = spw1t + 128 * 288;              // 128*288
    unsigned* w2ph = (unsigned*)(cfw1t + 128 * 288);  // 128 u32 (f16 pairs)
    unsigned* w3ph = w2ph + 128;                      // 8 u32
    float* qs_t  = (float*)(w3ph + 8);                // 256*2048 f32 (own slot)
    float* out   = (float*)d_out;

    k_prepall<<<1057, 256, 0, stream>>>(gate_w1, gate_w2, bb_w, safe_w1, spec_w1,
                                        conf_w1, qs, stem_w2, stem_w3,
                                        w1t, w2t, bbt, sw1t, spw1t, cfw1t, qs_t,
                                        w2ph, w3ph);
    k_calib7<<<512, 256, 0, stream>>>(x_num, center, scale, qs, qs_t,
                                      stem_w1, stem_b1, w2ph, stem_b2, w3ph, stem_b3,
                                      x_cal);
    k_fused<<<512, 256, 0, stream>>>(x_cal, w1t, gate_b1, w2t, gate_b2, bbt, bb_b,
                                     g, h_b);
    k_topk<<<B / 4, 256, 0, stream>>>(g, x_cal, top_w1, top_b1, top_w2, top_b2, z_top, gstat);
    k_tail3<<<B / 16, 256, 0, stream>>>(h_b, z_top, gstat,
                                        base_w, base_b,
                                        safe_lg, safe_lb, sw1t, safe_b1, safe_w2, safe_b2,
                                        spec_lg, spec_lb, spw1t, spec_b1, spec_w2, spec_b2,
                                        conf_lg, conf_lb, cfw1t, conf_b1, conf_w2, conf_b2,
                                        out);
}